// Round 6
// baseline (351.827 us; speedup 1.0000x reference)
//
#include <hip/hip_runtime.h>
#include <math.h>

#define IN_F 128
#define OUT_F 32
#define HEADS 4
#define HC 128  // HEADS*OUT_F
#define NEG_SLOPE 0.2f
#define LOG2E 1.44269504088896f

// ---------------------------------------------------------------------------
// 1) Projection GEMM: [N x 128] @ [128 x 256] -> xl | xr.
//    One 256-thread block per 32-node tile; W read once per block.
//    Layout: 32 colgroups x 8 rowgroups; each thread = 4 rows x 8 cols.
//    FMA : ds_read_b128 ratio = 32:1 (was 16:1) — off the LDS-pipe limit.
// ---------------------------------------------------------------------------
#define FMA4(A, S, W) \
    (A).x = fmaf((S), (W).x, (A).x); (A).y = fmaf((S), (W).y, (A).y); \
    (A).z = fmaf((S), (W).z, (A).z); (A).w = fmaf((S), (W).w, (A).w);

__global__ void __launch_bounds__(256)
proj_kernel(const float* __restrict__ x,
            const float* __restrict__ Wl,
            const float* __restrict__ Wr,
            float* __restrict__ xl,
            float* __restrict__ xr, int N) {
    __shared__ float xs[32 * IN_F];  // 16 KB
    const int tid = threadIdx.x;
    const int n0 = blockIdx.x * 32;
    const int rows = min(32, N - n0);

    const float4* x4 = (const float4*)(x + (size_t)n0 * IN_F);
    float4* xs4 = (float4*)xs;
    const int nval4 = rows * (IN_F / 4);
#pragma unroll
    for (int q = 0; q < 4; ++q) {
        const int idx = q * 256 + tid;
        xs4[idx] = (idx < nval4) ? x4[idx] : make_float4(0.f, 0.f, 0.f, 0.f);
    }
    __syncthreads();

    const int cg = tid & 31;   // column group: 8 consecutive cols
    const int rg = tid >> 5;   // row group: 4 consecutive rows
    const float* Wp;
    float* outp;
    int cb;
    if (cg < 16) { Wp = Wl; outp = xl; cb = cg * 8; }
    else         { Wp = Wr; outp = xr; cb = (cg - 16) * 8; }

    float4 acc0[4], acc1[4];
#pragma unroll
    for (int r = 0; r < 4; ++r) {
        acc0[r] = make_float4(0.f, 0.f, 0.f, 0.f);
        acc1[r] = make_float4(0.f, 0.f, 0.f, 0.f);
    }

    const float* xrow = xs + rg * 4 * IN_F;
#pragma unroll 2
    for (int k = 0; k < IN_F; k += 4) {
        float4 wa[4], wb[4];
#pragma unroll
        for (int kk = 0; kk < 4; ++kk) {
            wa[kk] = *(const float4*)&Wp[(k + kk) * HC + cb];
            wb[kk] = *(const float4*)&Wp[(k + kk) * HC + cb + 4];
        }
#pragma unroll
        for (int r = 0; r < 4; ++r) {
            const float4 xv = *(const float4*)&xrow[r * IN_F + k];  // LDS b128
            FMA4(acc0[r], xv.x, wa[0]); FMA4(acc1[r], xv.x, wb[0]);
            FMA4(acc0[r], xv.y, wa[1]); FMA4(acc1[r], xv.y, wb[1]);
            FMA4(acc0[r], xv.z, wa[2]); FMA4(acc1[r], xv.z, wb[2]);
            FMA4(acc0[r], xv.w, wa[3]); FMA4(acc1[r], xv.w, wb[3]);
        }
    }

#pragma unroll
    for (int r = 0; r < 4; ++r) {
        const int rr = rg * 4 + r;
        if (rr < rows) {
            *(float4*)&outp[(size_t)(n0 + rr) * HC + cb] = acc0[r];
            *(float4*)&outp[(size_t)(n0 + rr) * HC + cb + 4] = acc1[r];
        }
    }
}

// ---------------------------------------------------------------------------
// 2) CSR build: deg histogram -> contiguous region alloc -> scatter src ids
// ---------------------------------------------------------------------------
__global__ void zero_kernel(int* __restrict__ deg, int* __restrict__ fill,
                            unsigned int* __restrict__ cursor, int N) {
    const int t = blockIdx.x * blockDim.x + threadIdx.x;
    if (t < N) { deg[t] = 0; fill[t] = 0; }
    if (t == 0) *cursor = 0u;
}

__global__ void hist_kernel(const int* __restrict__ ei, int* __restrict__ deg,
                            int E0, int Etot) {
    const int t = blockIdx.x * blockDim.x + threadIdx.x;
    if (t >= Etot) return;
    const int dst = (t < E0) ? ei[E0 + t] : (t - E0);
    atomicAdd(&deg[dst], 1);
}

__global__ void alloc_kernel(const int* __restrict__ deg,
                             int* __restrict__ start,
                             unsigned int* __restrict__ cursor, int N) {
    __shared__ int sc[256];
    __shared__ int base_s;
    const int tid = threadIdx.x;
    const int n = blockIdx.x * 256 + tid;
    const int d = (n < N) ? deg[n] : 0;
    sc[tid] = d;
    __syncthreads();
#pragma unroll
    for (int off = 1; off < 256; off <<= 1) {
        int v = (tid >= off) ? sc[tid - off] : 0;
        __syncthreads();
        sc[tid] += v;
        __syncthreads();
    }
    if (tid == 255) base_s = (int)atomicAdd(cursor, (unsigned int)sc[255]);
    __syncthreads();
    if (n < N) start[n] = base_s + sc[tid] - d;  // exclusive
}

__global__ void scatter_kernel(const int* __restrict__ ei,
                               const int* __restrict__ start,
                               int* __restrict__ fill,
                               int* __restrict__ esrc,
                               int E0, int Etot) {
    const int t = blockIdx.x * blockDim.x + threadIdx.x;
    if (t >= Etot) return;
    int src, dst;
    if (t < E0) { src = ei[t]; dst = ei[E0 + t]; }
    else        { src = dst = t - E0; }
    const int pos = start[dst] + atomicAdd(&fill[dst], 1);
    esrc[pos] = src;
}

// ---------------------------------------------------------------------------
// 3) Fused attention + softmax + aggregation (no segment-max: logits are
//    O(1)-bounded, softmax shift-invariant — validated R4/R5).
//    Branch-free 2-edge-unrolled inner loop, DPP 32-lane reduce.
// ---------------------------------------------------------------------------
template <int CTRL>
__device__ __forceinline__ float dpp_add(float v) {
    const int t = __builtin_amdgcn_update_dpp(
        0, __float_as_int(v), CTRL, 0xF, 0xF, true);
    return v + __int_as_float(t);
}

__global__ void __launch_bounds__(128)
fused_agg_kernel(const float* __restrict__ xl,
                 const float* __restrict__ xr,
                 const float* __restrict__ att,
                 const float* __restrict__ bias,
                 const int* __restrict__ esrc,
                 const int* __restrict__ start,
                 const int* __restrict__ deg,
                 float* __restrict__ out, int EtotM1) {
    __shared__ int les[132];
    const int n = blockIdx.x;
    const int i = threadIdx.x;                 // channel 0..127
    const bool hiGroup = ((i & 63) >= 32);
    const float xr_i = xr[(size_t)n * HC + i];
    const float au  = att[i] * LOG2E;          // fold log2e -> exp2
    const float au2 = au * NEG_SLOPE;
    const int s0 = start[n];
    const int d = deg[n];                      // >= 1 (self-loop)
    const float* __restrict__ xli = xl + i;

    float sum = 0.f, acc = 0.f;

    for (int jb = 0; jb < d; jb += 128) {
        const int cnt = min(128, d - jb);
        __syncthreads();
        les[i] = esrc[min(s0 + jb + i, EtotM1)];  // clamped: always a valid node id
        if (i < 4) les[128 + i] = 0;              // pad for unconditional prefetch
        __syncthreads();

        float vA = xli[(unsigned)les[0] << 7];
        float vB = xli[(unsigned)les[1] << 7];

        int j = 0;
        for (; j + 1 < cnt; j += 2) {
            // unconditional depth-2 prefetch (pad makes it safe)
            const float vC = xli[(unsigned)les[j + 2] << 7];
            const float vD = xli[(unsigned)les[j + 3] << 7];

            float sA = vA + xr_i;
            float sB = vB + xr_i;
            float cA = ((sA > 0.f) ? au : au2) * sA;
            float cB = ((sB > 0.f) ? au : au2) * sB;
            cA = dpp_add<0x111>(cA); cB = dpp_add<0x111>(cB);  // row_shr:1
            cA = dpp_add<0x112>(cA); cB = dpp_add<0x112>(cB);  // row_shr:2
            cA = dpp_add<0x114>(cA); cB = dpp_add<0x114>(cB);  // row_shr:4
            cA = dpp_add<0x118>(cA); cB = dpp_add<0x118>(cB);  // row_shr:8
            cA = dpp_add<0x142>(cA); cB = dpp_add<0x142>(cB);  // row_bcast:15
            const float a31 = __int_as_float(__builtin_amdgcn_readlane(__float_as_int(cA), 31));
            const float a63 = __int_as_float(__builtin_amdgcn_readlane(__float_as_int(cA), 63));
            const float b31 = __int_as_float(__builtin_amdgcn_readlane(__float_as_int(cB), 31));
            const float b63 = __int_as_float(__builtin_amdgcn_readlane(__float_as_int(cB), 63));
            const float pA = exp2f(hiGroup ? a63 : a31);
            const float pB = exp2f(hiGroup ? b63 : b31);
            sum += pA;
            acc = fmaf(pA, vA, acc);
            sum += pB;
            acc = fmaf(pB, vB, acc);

            vA = vC; vB = vD;
        }
        if (j < cnt) {  // tail edge
            float sA = vA + xr_i;
            float cA = ((sA > 0.f) ? au : au2) * sA;
            cA = dpp_add<0x111>(cA);
            cA = dpp_add<0x112>(cA);
            cA = dpp_add<0x114>(cA);
            cA = dpp_add<0x118>(cA);
            cA = dpp_add<0x142>(cA);
            const float a31 = __int_as_float(__builtin_amdgcn_readlane(__float_as_int(cA), 31));
            const float a63 = __int_as_float(__builtin_amdgcn_readlane(__float_as_int(cA), 63));
            const float pA = exp2f(hiGroup ? a63 : a31);
            sum += pA;
            acc = fmaf(pA, vA, acc);
        }
    }
    out[(size_t)n * HC + i] = acc / (sum + 1e-16f) + bias[i];
}

// ---------------------------------------------------------------------------
extern "C" void kernel_launch(void* const* d_in, const int* in_sizes, int n_in,
                              void* d_out, int out_size, void* d_ws, size_t ws_size,
                              hipStream_t stream) {
    const float* x    = (const float*)d_in[0];
    const int*   ei   = (const int*)d_in[1];   // harness delivers int inputs as int32
    const float* Wl   = (const float*)d_in[2];
    const float* Wr   = (const float*)d_in[3];
    const float* att  = (const float*)d_in[4];
    const float* bias = (const float*)d_in[5];
    float* out        = (float*)d_out;

    const int N    = in_sizes[0] / IN_F;   // 50000
    const int E0   = in_sizes[1] / 2;      // 800000
    const int Etot = E0 + N;               // 850000

    char* base = (char*)d_ws;
    float* xl   = (float*)base;        base += (size_t)N * HC * sizeof(float);
    float* xr   = (float*)base;        base += (size_t)N * HC * sizeof(float);
    int*   esrc = (int*)base;          base += (size_t)Etot * sizeof(int);
    int*   deg  = (int*)base;          base += (size_t)N * sizeof(int);
    int*   strt = (int*)base;          base += (size_t)N * sizeof(int);
    int*   fill = (int*)base;          base += (size_t)N * sizeof(int);
    unsigned int* cursor = (unsigned int*)base;

    proj_kernel<<<(N + 31) / 32, 256, 0, stream>>>(x, Wl, Wr, xl, xr, N);

    zero_kernel<<<(N + 255) / 256, 256, 0, stream>>>(deg, fill, cursor, N);
    hist_kernel<<<(Etot + 255) / 256, 256, 0, stream>>>(ei, deg, E0, Etot);
    alloc_kernel<<<(N + 255) / 256, 256, 0, stream>>>(deg, strt, cursor, N);
    scatter_kernel<<<(Etot + 255) / 256, 256, 0, stream>>>(ei, strt, fill, esrc, E0, Etot);

    fused_agg_kernel<<<N, HC, 0, stream>>>(xl, xr, att, bias, esrc, strt, deg, out, Etot - 1);
}

// Round 7
// 294.714 us; speedup vs baseline: 1.1938x; 1.1938x over previous
//
#include <hip/hip_runtime.h>
#include <math.h>

#define IN_F 128
#define OUT_F 32
#define HEADS 4
#define HC 128  // HEADS*OUT_F
#define NEG_SLOPE 0.2f
#define LOG2E 1.44269504088896f

// ---------------------------------------------------------------------------
// 1) Projection GEMM: [N x 128] @ [128 x 256] -> xl | xr.
//    R5 tiling (verified fast): one 256-thread block per 32-node tile,
//    64 col-groups x 4 cols (dense 16B-stride W loads), 4 row-groups x 8 rows.
//    R6's 8-col-group variant regressed 3.4x: 32B-stride lanes (half-dense
//    cachelines) + 8x W duplication -> L2-fetch-bound.  Do not re-widen.
// ---------------------------------------------------------------------------
__global__ void __launch_bounds__(256)
proj_kernel(const float* __restrict__ x,
            const float* __restrict__ Wl,
            const float* __restrict__ Wr,
            float* __restrict__ xl,
            float* __restrict__ xr, int N) {
    __shared__ float xs[32 * IN_F];  // 16 KB
    const int tid = threadIdx.x;
    const int n0 = blockIdx.x * 32;
    const int rows = min(32, N - n0);

    const float4* x4 = (const float4*)(x + (size_t)n0 * IN_F);
    float4* xs4 = (float4*)xs;
    const int nval4 = rows * (IN_F / 4);
#pragma unroll
    for (int q = 0; q < 4; ++q) {
        const int idx = q * 256 + tid;
        xs4[idx] = (idx < nval4) ? x4[idx] : make_float4(0.f, 0.f, 0.f, 0.f);
    }
    __syncthreads();

    const int cg = tid & 63;   // column group: 4 consecutive cols (dense lanes)
    const int rg = tid >> 6;   // row group: 8 consecutive rows
    const float* Wp;
    float* outp;
    int cb;
    if (cg < 32) { Wp = Wl; outp = xl; cb = cg * 4; }
    else         { Wp = Wr; outp = xr; cb = (cg - 32) * 4; }

    float4 acc[8];
#pragma unroll
    for (int r = 0; r < 8; ++r) acc[r] = make_float4(0.f, 0.f, 0.f, 0.f);

    const float* xrow = xs + rg * 8 * IN_F;
#pragma unroll 4
    for (int k = 0; k < IN_F; k += 4) {
        const float4 wv0 = *(const float4*)&Wp[(k + 0) * HC + cb];
        const float4 wv1 = *(const float4*)&Wp[(k + 1) * HC + cb];
        const float4 wv2 = *(const float4*)&Wp[(k + 2) * HC + cb];
        const float4 wv3 = *(const float4*)&Wp[(k + 3) * HC + cb];
#pragma unroll
        for (int r = 0; r < 8; ++r) {
            const float4 xv = *(const float4*)&xrow[r * IN_F + k];  // LDS b128
            acc[r].x += xv.x * wv0.x; acc[r].y += xv.x * wv0.y;
            acc[r].z += xv.x * wv0.z; acc[r].w += xv.x * wv0.w;
            acc[r].x += xv.y * wv1.x; acc[r].y += xv.y * wv1.y;
            acc[r].z += xv.y * wv1.z; acc[r].w += xv.y * wv1.w;
            acc[r].x += xv.z * wv2.x; acc[r].y += xv.z * wv2.y;
            acc[r].z += xv.z * wv2.z; acc[r].w += xv.z * wv2.w;
            acc[r].x += xv.w * wv3.x; acc[r].y += xv.w * wv3.y;
            acc[r].z += xv.w * wv3.z; acc[r].w += xv.w * wv3.w;
        }
    }

#pragma unroll
    for (int r = 0; r < 8; ++r) {
        const int rr = rg * 8 + r;
        if (rr < rows) *(float4*)&outp[(size_t)(n0 + rr) * HC + cb] = acc[r];
    }
}

// ---------------------------------------------------------------------------
// 2) CSR build: deg histogram -> contiguous region alloc -> scatter src ids
// ---------------------------------------------------------------------------
__global__ void zero_kernel(int* __restrict__ deg, int* __restrict__ fill,
                            unsigned int* __restrict__ cursor, int N) {
    const int t = blockIdx.x * blockDim.x + threadIdx.x;
    if (t < N) { deg[t] = 0; fill[t] = 0; }
    if (t == 0) *cursor = 0u;
}

__global__ void hist_kernel(const int* __restrict__ ei, int* __restrict__ deg,
                            int E0, int Etot) {
    const int t = blockIdx.x * blockDim.x + threadIdx.x;
    if (t >= Etot) return;
    const int dst = (t < E0) ? ei[E0 + t] : (t - E0);
    atomicAdd(&deg[dst], 1);
}

__global__ void alloc_kernel(const int* __restrict__ deg,
                             int* __restrict__ start,
                             unsigned int* __restrict__ cursor, int N) {
    __shared__ int sc[256];
    __shared__ int base_s;
    const int tid = threadIdx.x;
    const int n = blockIdx.x * 256 + tid;
    const int d = (n < N) ? deg[n] : 0;
    sc[tid] = d;
    __syncthreads();
#pragma unroll
    for (int off = 1; off < 256; off <<= 1) {
        int v = (tid >= off) ? sc[tid - off] : 0;
        __syncthreads();
        sc[tid] += v;
        __syncthreads();
    }
    if (tid == 255) base_s = (int)atomicAdd(cursor, (unsigned int)sc[255]);
    __syncthreads();
    if (n < N) start[n] = base_s + sc[tid] - d;  // exclusive
}

__global__ void scatter_kernel(const int* __restrict__ ei,
                               const int* __restrict__ start,
                               int* __restrict__ fill,
                               int* __restrict__ esrc,
                               int E0, int Etot) {
    const int t = blockIdx.x * blockDim.x + threadIdx.x;
    if (t >= Etot) return;
    int src, dst;
    if (t < E0) { src = ei[t]; dst = ei[E0 + t]; }
    else        { src = dst = t - E0; }
    const int pos = start[dst] + atomicAdd(&fill[dst], 1);
    esrc[pos] = src;
}

// ---------------------------------------------------------------------------
// 3) Fused attention + softmax + aggregation (no segment-max: logits are
//    O(1)-bounded, softmax shift-invariant — validated R4-R6).
//    Branch-free 2-edge-unrolled inner loop, DPP 32-lane reduce. (R6 win.)
// ---------------------------------------------------------------------------
template <int CTRL>
__device__ __forceinline__ float dpp_add(float v) {
    const int t = __builtin_amdgcn_update_dpp(
        0, __float_as_int(v), CTRL, 0xF, 0xF, true);
    return v + __int_as_float(t);
}

__global__ void __launch_bounds__(128)
fused_agg_kernel(const float* __restrict__ xl,
                 const float* __restrict__ xr,
                 const float* __restrict__ att,
                 const float* __restrict__ bias,
                 const int* __restrict__ esrc,
                 const int* __restrict__ start,
                 const int* __restrict__ deg,
                 float* __restrict__ out, int EtotM1) {
    __shared__ int les[132];
    const int n = blockIdx.x;
    const int i = threadIdx.x;                 // channel 0..127
    const bool hiGroup = ((i & 63) >= 32);
    const float xr_i = xr[(size_t)n * HC + i];
    const float au  = att[i] * LOG2E;          // fold log2e -> exp2
    const float au2 = au * NEG_SLOPE;
    const int s0 = start[n];
    const int d = deg[n];                      // >= 1 (self-loop)
    const float* __restrict__ xli = xl + i;

    float sum = 0.f, acc = 0.f;

    for (int jb = 0; jb < d; jb += 128) {
        const int cnt = min(128, d - jb);
        __syncthreads();
        les[i] = esrc[min(s0 + jb + i, EtotM1)];  // clamped: always a valid node id
        if (i < 4) les[128 + i] = 0;              // pad for unconditional prefetch
        __syncthreads();

        float vA = xli[(unsigned)les[0] << 7];
        float vB = xli[(unsigned)les[1] << 7];

        int j = 0;
        for (; j + 1 < cnt; j += 2) {
            const float vC = xli[(unsigned)les[j + 2] << 7];
            const float vD = xli[(unsigned)les[j + 3] << 7];

            float sA = vA + xr_i;
            float sB = vB + xr_i;
            float cA = ((sA > 0.f) ? au : au2) * sA;
            float cB = ((sB > 0.f) ? au : au2) * sB;
            cA = dpp_add<0x111>(cA); cB = dpp_add<0x111>(cB);  // row_shr:1
            cA = dpp_add<0x112>(cA); cB = dpp_add<0x112>(cB);  // row_shr:2
            cA = dpp_add<0x114>(cA); cB = dpp_add<0x114>(cB);  // row_shr:4
            cA = dpp_add<0x118>(cA); cB = dpp_add<0x118>(cB);  // row_shr:8
            cA = dpp_add<0x142>(cA); cB = dpp_add<0x142>(cB);  // row_bcast:15
            const float a31 = __int_as_float(__builtin_amdgcn_readlane(__float_as_int(cA), 31));
            const float a63 = __int_as_float(__builtin_amdgcn_readlane(__float_as_int(cA), 63));
            const float b31 = __int_as_float(__builtin_amdgcn_readlane(__float_as_int(cB), 31));
            const float b63 = __int_as_float(__builtin_amdgcn_readlane(__float_as_int(cB), 63));
            const float pA = exp2f(hiGroup ? a63 : a31);
            const float pB = exp2f(hiGroup ? b63 : b31);
            sum += pA;
            acc = fmaf(pA, vA, acc);
            sum += pB;
            acc = fmaf(pB, vB, acc);

            vA = vC; vB = vD;
        }
        if (j < cnt) {  // tail edge
            float sA = vA + xr_i;
            float cA = ((sA > 0.f) ? au : au2) * sA;
            cA = dpp_add<0x111>(cA);
            cA = dpp_add<0x112>(cA);
            cA = dpp_add<0x114>(cA);
            cA = dpp_add<0x118>(cA);
            cA = dpp_add<0x142>(cA);
            const float a31 = __int_as_float(__builtin_amdgcn_readlane(__float_as_int(cA), 31));
            const float a63 = __int_as_float(__builtin_amdgcn_readlane(__float_as_int(cA), 63));
            const float pA = exp2f(hiGroup ? a63 : a31);
            sum += pA;
            acc = fmaf(pA, vA, acc);
        }
    }
    out[(size_t)n * HC + i] = acc / (sum + 1e-16f) + bias[i];
}

// ---------------------------------------------------------------------------
extern "C" void kernel_launch(void* const* d_in, const int* in_sizes, int n_in,
                              void* d_out, int out_size, void* d_ws, size_t ws_size,
                              hipStream_t stream) {
    const float* x    = (const float*)d_in[0];
    const int*   ei   = (const int*)d_in[1];   // harness delivers int inputs as int32
    const float* Wl   = (const float*)d_in[2];
    const float* Wr   = (const float*)d_in[3];
    const float* att  = (const float*)d_in[4];
    const float* bias = (const float*)d_in[5];
    float* out        = (float*)d_out;

    const int N    = in_sizes[0] / IN_F;   // 50000
    const int E0   = in_sizes[1] / 2;      // 800000
    const int Etot = E0 + N;               // 850000

    char* base = (char*)d_ws;
    float* xl   = (float*)base;        base += (size_t)N * HC * sizeof(float);
    float* xr   = (float*)base;        base += (size_t)N * HC * sizeof(float);
    int*   esrc = (int*)base;          base += (size_t)Etot * sizeof(int);
    int*   deg  = (int*)base;          base += (size_t)N * sizeof(int);
    int*   strt = (int*)base;          base += (size_t)N * sizeof(int);
    int*   fill = (int*)base;          base += (size_t)N * sizeof(int);
    unsigned int* cursor = (unsigned int*)base;

    proj_kernel<<<(N + 31) / 32, 256, 0, stream>>>(x, Wl, Wr, xl, xr, N);

    zero_kernel<<<(N + 255) / 256, 256, 0, stream>>>(deg, fill, cursor, N);
    hist_kernel<<<(Etot + 255) / 256, 256, 0, stream>>>(ei, deg, E0, Etot);
    alloc_kernel<<<(N + 255) / 256, 256, 0, stream>>>(deg, strt, cursor, N);
    scatter_kernel<<<(Etot + 255) / 256, 256, 0, stream>>>(ei, strt, fill, esrc, E0, Etot);

    fused_agg_kernel<<<N, HC, 0, stream>>>(xl, xr, att, bias, esrc, strt, deg, out, Etot - 1);
}

// Round 8
// 284.582 us; speedup vs baseline: 1.2363x; 1.0356x over previous
//
#include <hip/hip_runtime.h>
#include <math.h>

#define IN_F 128
#define OUT_F 32
#define HEADS 4
#define HC 128  // HEADS*OUT_F
#define NEG_SLOPE 0.2f
#define LOG2E 1.44269504088896f

// ---------------------------------------------------------------------------
// 1) Projection GEMM: [N x 128] @ [128 x 256] -> xl | xr.
//    R5 tiling (verified fast): 64 col-groups x 4 cols (dense 16B-stride W
//    loads, 4x W reuse), 4 row-groups x 8 rows.  R6's 8-col variant regressed
//    3.4x (32B-stride half-dense cachelines, 8x W duplication) — keep as-is.
// ---------------------------------------------------------------------------
__global__ void __launch_bounds__(256)
proj_kernel(const float* __restrict__ x,
            const float* __restrict__ Wl,
            const float* __restrict__ Wr,
            float* __restrict__ xl,
            float* __restrict__ xr, int N) {
    __shared__ float xs[32 * IN_F];  // 16 KB
    const int tid = threadIdx.x;
    const int n0 = blockIdx.x * 32;
    const int rows = min(32, N - n0);

    const float4* x4 = (const float4*)(x + (size_t)n0 * IN_F);
    float4* xs4 = (float4*)xs;
    const int nval4 = rows * (IN_F / 4);
#pragma unroll
    for (int q = 0; q < 4; ++q) {
        const int idx = q * 256 + tid;
        xs4[idx] = (idx < nval4) ? x4[idx] : make_float4(0.f, 0.f, 0.f, 0.f);
    }
    __syncthreads();

    const int cg = tid & 63;   // column group: 4 consecutive cols (dense lanes)
    const int rg = tid >> 6;   // row group: 8 consecutive rows
    const float* Wp;
    float* outp;
    int cb;
    if (cg < 32) { Wp = Wl; outp = xl; cb = cg * 4; }
    else         { Wp = Wr; outp = xr; cb = (cg - 32) * 4; }

    float4 acc[8];
#pragma unroll
    for (int r = 0; r < 8; ++r) acc[r] = make_float4(0.f, 0.f, 0.f, 0.f);

    const float* xrow = xs + rg * 8 * IN_F;
#pragma unroll 4
    for (int k = 0; k < IN_F; k += 4) {
        const float4 wv0 = *(const float4*)&Wp[(k + 0) * HC + cb];
        const float4 wv1 = *(const float4*)&Wp[(k + 1) * HC + cb];
        const float4 wv2 = *(const float4*)&Wp[(k + 2) * HC + cb];
        const float4 wv3 = *(const float4*)&Wp[(k + 3) * HC + cb];
#pragma unroll
        for (int r = 0; r < 8; ++r) {
            const float4 xv = *(const float4*)&xrow[r * IN_F + k];  // LDS b128
            acc[r].x += xv.x * wv0.x; acc[r].y += xv.x * wv0.y;
            acc[r].z += xv.x * wv0.z; acc[r].w += xv.x * wv0.w;
            acc[r].x += xv.y * wv1.x; acc[r].y += xv.y * wv1.y;
            acc[r].z += xv.y * wv1.z; acc[r].w += xv.y * wv1.w;
            acc[r].x += xv.z * wv2.x; acc[r].y += xv.z * wv2.y;
            acc[r].z += xv.z * wv2.z; acc[r].w += xv.z * wv2.w;
            acc[r].x += xv.w * wv3.x; acc[r].y += xv.w * wv3.y;
            acc[r].z += xv.w * wv3.z; acc[r].w += xv.w * wv3.w;
        }
    }

#pragma unroll
    for (int r = 0; r < 8; ++r) {
        const int rr = rg * 8 + r;
        if (rr < rows) *(float4*)&outp[(size_t)(n0 + rr) * HC + cb] = acc[r];
    }
}

// ---------------------------------------------------------------------------
// 2) CSR build (zeroing now done by one hipMemsetAsync over deg|fill|cursor)
// ---------------------------------------------------------------------------
__global__ void hist_kernel(const int* __restrict__ ei, int* __restrict__ deg,
                            int E0, int Etot) {
    const int t = blockIdx.x * blockDim.x + threadIdx.x;
    if (t >= Etot) return;
    const int dst = (t < E0) ? ei[E0 + t] : (t - E0);
    atomicAdd(&deg[dst], 1);
}

__global__ void alloc_kernel(const int* __restrict__ deg,
                             int* __restrict__ start,
                             unsigned int* __restrict__ cursor, int N) {
    __shared__ int sc[256];
    __shared__ int base_s;
    const int tid = threadIdx.x;
    const int n = blockIdx.x * 256 + tid;
    const int d = (n < N) ? deg[n] : 0;
    sc[tid] = d;
    __syncthreads();
#pragma unroll
    for (int off = 1; off < 256; off <<= 1) {
        int v = (tid >= off) ? sc[tid - off] : 0;
        __syncthreads();
        sc[tid] += v;
        __syncthreads();
    }
    if (tid == 255) base_s = (int)atomicAdd(cursor, (unsigned int)sc[255]);
    __syncthreads();
    if (n < N) start[n] = base_s + sc[tid] - d;  // exclusive
}

__global__ void scatter_kernel(const int* __restrict__ ei,
                               const int* __restrict__ start,
                               int* __restrict__ fill,
                               int* __restrict__ esrc,
                               int E0, int Etot) {
    const int t = blockIdx.x * blockDim.x + threadIdx.x;
    if (t >= Etot) return;
    int src, dst;
    if (t < E0) { src = ei[t]; dst = ei[E0 + t]; }
    else        { src = dst = t - E0; }
    const int pos = start[dst] + atomicAdd(&fill[dst], 1);
    esrc[pos] = src;
}

// ---------------------------------------------------------------------------
// 3) Fused attention + softmax + aggregation.  ONE WAVE PER NODE: lane l owns
//    channels (2l, 2l+1) — heads align with 16-lane DPP rows, so the logit
//    reduce is 4 dpp-adds + one ds_swizzle broadcast (0x1F0: lane -> its
//    row's lane15).  No segment-max (logits O(1)-bounded; validated R4-R7).
//    Block = 4 independent waves = 4 nodes; no __syncthreads.
// ---------------------------------------------------------------------------
template <int CTRL>
__device__ __forceinline__ float dpp_add(float v) {
    const int t = __builtin_amdgcn_update_dpp(
        0, __float_as_int(v), CTRL, 0xF, 0xF, true);
    return v + __int_as_float(t);
}

__device__ __forceinline__ float row_sum_bcast(float c) {
    c = dpp_add<0x111>(c);  // row_shr:1
    c = dpp_add<0x112>(c);  // row_shr:2
    c = dpp_add<0x114>(c);  // row_shr:4
    c = dpp_add<0x118>(c);  // row_shr:8 -> lane15 of each 16-row = row sum
    // broadcast row's lane15 to all its lanes: BitMode and=0x10,or=0x0F,xor=0
    return __int_as_float(
        __builtin_amdgcn_ds_swizzle(__float_as_int(c), 0x01F0));
}

__global__ void __launch_bounds__(256)
fused_agg_kernel(const float* __restrict__ xl,
                 const float* __restrict__ xr,
                 const float* __restrict__ att,
                 const float* __restrict__ bias,
                 const int* __restrict__ esrc,
                 const int* __restrict__ start,
                 const int* __restrict__ deg,
                 float* __restrict__ out, int N, int EtotM1) {
    __shared__ int les_all[4][68];
    const int wid = threadIdx.x >> 6;
    const int lane = threadIdx.x & 63;
    const int n = blockIdx.x * 4 + wid;
    if (n >= N) return;
    int* les = les_all[wid];

    const int ch = lane * 2;  // channel pair (ch, ch+1); head = lane>>4
    const float2 xr2 = *(const float2*)&xr[(size_t)n * HC + ch];
    const float2 at2 = *(const float2*)&att[ch];
    const float au0 = at2.x * LOG2E, au1 = at2.y * LOG2E;
    const float an0 = au0 * NEG_SLOPE, an1 = au1 * NEG_SLOPE;
    const int s0 = start[n];
    const int d = deg[n];                      // >= 1 (self-loop)
    const float* __restrict__ xlc = xl + ch;

    float sum = 0.f, ax = 0.f, ay = 0.f;

    for (int jb = 0; jb < d; jb += 64) {
        const int cnt = min(64, d - jb);
        les[lane] = esrc[min(s0 + jb + lane, EtotM1)];  // clamped: valid id
        if (lane < 4) les[64 + lane] = 0;               // pad for prefetch

        float2 vA = *(const float2*)&xlc[(size_t)(unsigned)les[0] * HC];
        float2 vB = *(const float2*)&xlc[(size_t)(unsigned)les[1] * HC];

        int j = 0;
        for (; j + 1 < cnt; j += 2) {
            const float2 vC = *(const float2*)&xlc[(size_t)(unsigned)les[j + 2] * HC];
            const float2 vD = *(const float2*)&xlc[(size_t)(unsigned)les[j + 3] * HC];

            // edge A
            {
                const float sx = vA.x + xr2.x;
                const float sy = vA.y + xr2.y;
                float c = ((sx > 0.f) ? au0 : an0) * sx;
                c = fmaf(((sy > 0.f) ? au1 : an1), sy, c);
                const float p = exp2f(row_sum_bcast(c));
                sum += p;
                ax = fmaf(p, vA.x, ax);
                ay = fmaf(p, vA.y, ay);
            }
            // edge B
            {
                const float sx = vB.x + xr2.x;
                const float sy = vB.y + xr2.y;
                float c = ((sx > 0.f) ? au0 : an0) * sx;
                c = fmaf(((sy > 0.f) ? au1 : an1), sy, c);
                const float p = exp2f(row_sum_bcast(c));
                sum += p;
                ax = fmaf(p, vB.x, ax);
                ay = fmaf(p, vB.y, ay);
            }
            vA = vC; vB = vD;
        }
        if (j < cnt) {  // tail edge
            const float sx = vA.x + xr2.x;
            const float sy = vA.y + xr2.y;
            float c = ((sx > 0.f) ? au0 : an0) * sx;
            c = fmaf(((sy > 0.f) ? au1 : an1), sy, c);
            const float p = exp2f(row_sum_bcast(c));
            sum += p;
            ax = fmaf(p, vA.x, ax);
            ay = fmaf(p, vA.y, ay);
        }
    }
    const float inv = 1.f / (sum + 1e-16f);
    const float2 b2 = *(const float2*)&bias[ch];
    float2 o;
    o.x = fmaf(ax, inv, b2.x);
    o.y = fmaf(ay, inv, b2.y);
    *(float2*)&out[(size_t)n * HC + ch] = o;
}

// ---------------------------------------------------------------------------
extern "C" void kernel_launch(void* const* d_in, const int* in_sizes, int n_in,
                              void* d_out, int out_size, void* d_ws, size_t ws_size,
                              hipStream_t stream) {
    const float* x    = (const float*)d_in[0];
    const int*   ei   = (const int*)d_in[1];   // harness delivers int inputs as int32
    const float* Wl   = (const float*)d_in[2];
    const float* Wr   = (const float*)d_in[3];
    const float* att  = (const float*)d_in[4];
    const float* bias = (const float*)d_in[5];
    float* out        = (float*)d_out;

    const int N    = in_sizes[0] / IN_F;   // 50000
    const int E0   = in_sizes[1] / 2;      // 800000
    const int Etot = E0 + N;               // 850000

    char* base = (char*)d_ws;
    float* xl   = (float*)base;        base += (size_t)N * HC * sizeof(float);
    float* xr   = (float*)base;        base += (size_t)N * HC * sizeof(float);
    int*   esrc = (int*)base;          base += (size_t)Etot * sizeof(int);
    // contiguous zero region: deg | fill | cursor
    int*   deg  = (int*)base;          base += (size_t)N * sizeof(int);
    int*   fill = (int*)base;          base += (size_t)N * sizeof(int);
    unsigned int* cursor = (unsigned int*)base; base += sizeof(unsigned int);
    int*   strt = (int*)base;

    proj_kernel<<<(N + 31) / 32, 256, 0, stream>>>(x, Wl, Wr, xl, xr, N);

    hipMemsetAsync(deg, 0, (size_t)(2 * N + 1) * sizeof(int), stream);
    hist_kernel<<<(Etot + 255) / 256, 256, 0, stream>>>(ei, deg, E0, Etot);
    alloc_kernel<<<(N + 255) / 256, 256, 0, stream>>>(deg, strt, cursor, N);
    scatter_kernel<<<(Etot + 255) / 256, 256, 0, stream>>>(ei, strt, fill, esrc, E0, Etot);

    fused_agg_kernel<<<(N + 3) / 4, 256, 0, stream>>>(xl, xr, att, bias, esrc, strt, deg,
                                                      out, N, Etot - 1);
}